// Round 7
// baseline (422.064 us; speedup 1.0000x reference)
//
#include <hip/hip_runtime.h>
#include <math.h>

// Problem constants (fixed by reference)
constexpr int Bc = 2, Sc = 2048, Dc = 512, Hc = 8, DHc = 64;
constexpr int NQKV = 3 * Dc;  // 1536

typedef unsigned short u16;
typedef unsigned int u32;
typedef __attribute__((ext_vector_type(8))) __bf16 bf16x8;
typedef __attribute__((ext_vector_type(16))) float f32x16;

#define MFMA32 __builtin_amdgcn_mfma_f32_32x32x16_bf16

// Truncation hi/lo split of two floats, packed: ret.x = (hi(b)<<16)|hi(a),
// ret.y = lo-pair. hi = truncate-to-bf16; lo = bf16(residual).
__device__ inline uint2 splitpack2(float a, float b) {
  u32 ua = __float_as_uint(a), ub = __float_as_uint(b);
  u32 hi = (ub & 0xFFFF0000u) | (ua >> 16);
  float ra = a - __uint_as_float(ua & 0xFFFF0000u);
  float rb = b - __uint_as_float(ub & 0xFFFF0000u);
  u32 lo = (__float_as_uint(rb) & 0xFFFF0000u) | (__float_as_uint(ra) >> 16);
  return uint2{hi, lo};
}
__device__ inline void split1(float v, u16& hi, u16& lo) {
  u32 u = __float_as_uint(v);
  hi = (u16)(u >> 16);
  float r = v - __uint_as_float(u & 0xFFFF0000u);
  lo = (u16)(__float_as_uint(r) >> 16);
}

// ---------------------------------------------------------------------------
// GEMM1 (MFMA): qkv = x @ W^T + b, fp32 inputs split to bf16 hi/lo inline
// during staging. Tiles 128x64, BK=32, 4 waves (2x2), 2 m-tiles per wave.
// Epilogue splits to Q/K [h][b][s][dh] and V^T [h][b][dh][s] bf16 planes.
// ---------------------------------------------------------------------------
__global__ __launch_bounds__(256, 2) void gemm1_mfma(
    const float* __restrict__ x, const float* __restrict__ W,
    const float* __restrict__ bias, u16* __restrict__ Qhi,
    u16* __restrict__ Qlo, u16* __restrict__ Khi, u16* __restrict__ Klo,
    u16* __restrict__ Vthi, u16* __restrict__ Vtlo) {
  __shared__ __align__(16) u16 Af[2][4][2][64][8];  // 16 KB
  __shared__ __align__(16) u16 Bf[2][2][2][64][8];  // 8 KB
  const int tid = threadIdx.x;
  const int wave = tid >> 6, lane = tid & 63, l31 = lane & 31, lhi = lane >> 5;
  const int wm = wave >> 1, wn = wave & 1;
  const int m0 = blockIdx.y * 128, n0 = blockIdx.x * 64;

  f32x16 acc[2];
#pragma unroll
  for (int r = 0; r < 16; ++r) {
    acc[0][r] = 0.f;
    acc[1][r] = 0.f;
  }

  for (int k0 = 0; k0 < 512; k0 += 32) {
    // stage A: 512 8-elem k-groups (128 m x 4), 2 per thread, split inline
#pragma unroll
    for (int i = 0; i < 2; ++i) {
      const int g = i * 256 + tid;
      const int m = g >> 2, kg = g & 3;
      const float* src = x + (size_t)(m0 + m) * 512 + k0 + kg * 8;
      const float4 v0 = *(const float4*)src;
      const float4 v1 = *(const float4*)(src + 4);
      const uint2 p0 = splitpack2(v0.x, v0.y), p1 = splitpack2(v0.z, v0.w);
      const uint2 p2 = splitpack2(v1.x, v1.y), p3 = splitpack2(v1.z, v1.w);
      *(uint4*)&Af[0][m >> 5][kg >> 1][(kg & 1) * 32 + (m & 31)][0] =
          uint4{p0.x, p1.x, p2.x, p3.x};
      *(uint4*)&Af[1][m >> 5][kg >> 1][(kg & 1) * 32 + (m & 31)][0] =
          uint4{p0.y, p1.y, p2.y, p3.y};
    }
    // stage B: 256 groups, 1 per thread
    {
      const int n = tid >> 2, kg = tid & 3;
      const float* src = W + (size_t)(n0 + n) * 512 + k0 + kg * 8;
      const float4 v0 = *(const float4*)src;
      const float4 v1 = *(const float4*)(src + 4);
      const uint2 p0 = splitpack2(v0.x, v0.y), p1 = splitpack2(v0.z, v0.w);
      const uint2 p2 = splitpack2(v1.x, v1.y), p3 = splitpack2(v1.z, v1.w);
      *(uint4*)&Bf[0][n >> 5][kg >> 1][(kg & 1) * 32 + (n & 31)][0] =
          uint4{p0.x, p1.x, p2.x, p3.x};
      *(uint4*)&Bf[1][n >> 5][kg >> 1][(kg & 1) * 32 + (n & 31)][0] =
          uint4{p0.y, p1.y, p2.y, p3.y};
    }
    __syncthreads();
#pragma unroll
    for (int t = 0; t < 2; ++t) {
      const bf16x8 bh = *(const bf16x8*)&Bf[0][wn][t][lane][0];
      const bf16x8 bl = *(const bf16x8*)&Bf[1][wn][t][lane][0];
#pragma unroll
      for (int ti = 0; ti < 2; ++ti) {
        const bf16x8 ah = *(const bf16x8*)&Af[0][wm * 2 + ti][t][lane][0];
        const bf16x8 al = *(const bf16x8*)&Af[1][wm * 2 + ti][t][lane][0];
        acc[ti] = MFMA32(ah, bh, acc[ti], 0, 0, 0);
        acc[ti] = MFMA32(ah, bl, acc[ti], 0, 0, 0);
        acc[ti] = MFMA32(al, bh, acc[ti], 0, 0, 0);
      }
    }
    __syncthreads();
  }

  // epilogue: C col (lane&31) = n, rows per reg. t3 uniform per wave.
  const int n = n0 + wn * 32 + l31;
  const float bn = bias[n];
  const int h = n / 192, rem = n - h * 192, t3 = rem >> 6, dh = rem & 63;
#pragma unroll
  for (int ti = 0; ti < 2; ++ti)
#pragma unroll
    for (int r = 0; r < 16; ++r) {
      const int m = m0 + wm * 64 + ti * 32 + (r & 3) + 8 * (r >> 2) + 4 * lhi;
      const int batch = m >> 11, s = m & 2047;
      const float val = acc[ti][r] + bn;
      u16 hi, lo;
      split1(val, hi, lo);
      const int hbq = h * 2 + batch;
      if (t3 == 2) {
        const size_t idx = ((size_t)hbq * 64 + dh) * 2048 + s;
        Vthi[idx] = hi;
        Vtlo[idx] = lo;
      } else {
        const size_t idx = ((size_t)hbq * 2048 + s) * 64 + dh;
        if (t3 == 0) {
          Qhi[idx] = hi;
          Qlo[idx] = lo;
        } else {
          Khi[idx] = hi;
          Klo[idx] = lo;
        }
      }
    }
}

// ---------------------------------------------------------------------------
// MFMA flash attention, R7: fully register-pipelined. Per iter, the next
// iter's K/V (staging regs) and shift/mask (per-lane direct float4) loads are
// issued right after the first barrier and consumed a full compute-phase
// later. shift/mask fuse into sa[16] = mask ? hs*shift : 1e9 at iter bottom.
// No Sa LDS, no input clobber. Block = 4 waves = (wq 0..1)x(wk 0..1), 64 q.
// LDS 48 KB: Kf 16K | Vf 16K | Pf 16K (per-wave chunks). 2 barriers/iter.
// ---------------------------------------------------------------------------
__global__ __launch_bounds__(256, 2) void attn_mfma(
    const u16* __restrict__ Qhi, const u16* __restrict__ Qlo,
    const u16* __restrict__ Khi, const u16* __restrict__ Klo,
    const u16* __restrict__ Vthi, const u16* __restrict__ Vtlo,
    const float* __restrict__ shift, const float* __restrict__ mask,
    u16* __restrict__ Othi, u16* __restrict__ Otlo) {
  const int h = blockIdx.z, b = blockIdx.y;
  const int qb = blockIdx.x;
  const int tid = threadIdx.x;
  const int wave = tid >> 6;
  const int wq = wave >> 1, wk = wave & 1;
  const int lane = tid & 63;
  const int l31 = lane & 31, lhi = lane >> 5;

  __shared__ __align__(16) u16 smem[24576];  // Kf 8192 | Vf 8192 | Pf 8192 u16
  u16* Kf = smem;
  u16* Vf = smem + 8192;
  u16* Pw = smem + 16384 + wave * 2048;  // this wave's P chunk (hi | lo+1024)

  const size_t hb = (size_t)h * Bc + b;
  const int ql = wq * 32 + l31;  // q within block tile
  const int qg = qb * 64 + ql;   // global q

  // Q B-frags from global: n=q, k = t*16 + lhi*8 + j
  bf16x8 qf[2][4];
  {
    const size_t qbase = (hb * Sc + qg) * DHc;
#pragma unroll
    for (int t = 0; t < 4; ++t) {
      qf[0][t] = *(const bf16x8*)(Qhi + qbase + t * 16 + lhi * 8);
      qf[1][t] = *(const bf16x8*)(Qlo + qbase + t * 16 + lhi * 8);
    }
  }
  const float hs = exp2f(-(float)h);

  // per-lane SM row bases; per-iter key offset = it*64 + wk*32 + c*8 + lhi*4
  const float* shrow = shift + ((size_t)b * Sc + qg) * Sc + wk * 32 + lhi * 4;
  const float* mkrow = mask + ((size_t)b * Sc + qg) * Sc + wk * 32 + lhi * 4;

  // K/V staging source (per-thread fixed part)
  const int kr = lane >> 1, khalf = lane & 1;  // K: key row, dh half
  const size_t kfix = (hb * Sc + wk * 32 + kr) * 64 + khalf * 32;
  const size_t vfix = (hb * 64 + lane) * 2048 + wk * 32;

  float m_run = -INFINITY, l_run = 0.f;
  f32x16 o0, o1;
#pragma unroll
  for (int i = 0; i < 16; ++i) {
    o0[i] = 0.f;
    o1[i] = 0.f;
  }

  // ---- prologue: prefetch iter 0 K/V + fused sa
  uint4 kva[4], kvb[4];
  if (wq == 0) {
#pragma unroll
    for (int c = 0; c < 4; ++c) {
      kva[c] = *(const uint4*)(Khi + kfix + c * 8);
      kvb[c] = *(const uint4*)(Klo + kfix + c * 8);
    }
  } else {
#pragma unroll
    for (int c = 0; c < 4; ++c) {
      kva[c] = *(const uint4*)(Vthi + vfix + c * 8);
      kvb[c] = *(const uint4*)(Vtlo + vfix + c * 8);
    }
  }
  float sa[16];
#pragma unroll
  for (int c = 0; c < 4; ++c) {
    const float4 s4 = *(const float4*)(shrow + c * 8);
    const float4 m4 = *(const float4*)(mkrow + c * 8);
    sa[4 * c + 0] = (m4.x != 0.f) ? hs * s4.x : 1e9f;
    sa[4 * c + 1] = (m4.y != 0.f) ? hs * s4.y : 1e9f;
    sa[4 * c + 2] = (m4.z != 0.f) ? hs * s4.z : 1e9f;
    sa[4 * c + 3] = (m4.w != 0.f) ? hs * s4.w : 1e9f;
  }

  for (int it = 0; it < 32; ++it) {
    // ---- write prefetched K/V regs to LDS
    if (wq == 0) {
#pragma unroll
      for (int c = 0; c < 4; ++c) {
        const int dhc = khalf * 32 + c * 8;
        const int t = dhc >> 4, lh = (dhc >> 3) & 1;
        *(uint4*)&Kf[((wk * 4 + t) * 64 + lh * 32 + kr) * 8] = kva[c];
        *(uint4*)&Kf[(((2 + wk) * 4 + t) * 64 + lh * 32 + kr) * 8] = kvb[c];
      }
    } else {
      const int mt = lane >> 5, dl = lane & 31;
#pragma unroll
      for (int c = 0; c < 4; ++c) {
        const int t = c >> 1, lh = c & 1;
        *(uint4*)&Vf[(((wk * 2 + mt) * 2 + t) * 64 + lh * 32 + dl) * 8] = kva[c];
        *(uint4*)&Vf[((((2 + wk) * 2 + mt) * 2 + t) * 64 + lh * 32 + dl) * 8] =
            kvb[c];
      }
    }
    __syncthreads();

    // ---- issue next iter's prefetches (consumed a full compute-phase later)
    const int it2 = (it < 31) ? it + 1 : 31;
    float4 shn[4], mkn[4];
#pragma unroll
    for (int c = 0; c < 4; ++c) {
      shn[c] = *(const float4*)(shrow + (size_t)it2 * 64 + c * 8);
      mkn[c] = *(const float4*)(mkrow + (size_t)it2 * 64 + c * 8);
    }
    {
      const size_t koff = (size_t)it2 * 64 * 64;  // K advances 64 keys * 64 dh
      const size_t voff = (size_t)it2 * 64;       // V^T advances 64 along s
      if (wq == 0) {
#pragma unroll
        for (int c = 0; c < 4; ++c) {
          kva[c] = *(const uint4*)(Khi + kfix + koff + c * 8);
          kvb[c] = *(const uint4*)(Klo + kfix + koff + c * 8);
        }
      } else {
#pragma unroll
        for (int c = 0; c < 4; ++c) {
          kva[c] = *(const uint4*)(Vthi + vfix + voff + c * 8);
          kvb[c] = *(const uint4*)(Vtlo + vfix + voff + c * 8);
        }
      }
    }

    // ---- S^T = K·Q^T (m=key, n=q): Khi*Qhi + Khi*Qlo + Klo*Qhi
    f32x16 s;
#pragma unroll
    for (int i = 0; i < 16; ++i) s[i] = 0.f;
#pragma unroll
    for (int t = 0; t < 4; ++t) {
      const bf16x8 kh = *(const bf16x8*)&Kf[((wk * 4 + t) * 64 + lane) * 8];
      const bf16x8 kl = *(const bf16x8*)&Kf[(((2 + wk) * 4 + t) * 64 + lane) * 8];
      s = MFMA32(kh, qf[0][t], s, 0, 0, 0);
      s = MFMA32(kh, qf[1][t], s, 0, 0, 0);
      s = MFMA32(kl, qf[0][t], s, 0, 0, 0);
    }

    // ---- logits + online softmax (q = lane col; key = c*8 + lhi*4 + e)
    float p[16];
    float kmax = -INFINITY;
#pragma unroll
    for (int r = 0; r < 16; ++r) {
      const float lg = s[r] * 0.125f - sa[r];
      p[r] = lg;
      kmax = fmaxf(kmax, lg);
    }
    kmax = fmaxf(kmax, __shfl_xor(kmax, 32, 64));
    const float mnew = fmaxf(m_run, kmax);
    const float alpha = __expf(m_run - mnew);
    float rsum = 0.f;
#pragma unroll
    for (int r = 0; r < 16; ++r) {
      p[r] = __expf(p[r] - mnew);
      rsum += p[r];
    }
    rsum += __shfl_xor(rsum, 32, 64);
    l_run = l_run * alpha + rsum;
    m_run = mnew;
#pragma unroll
    for (int i = 0; i < 16; ++i) {
      o0[i] *= alpha;
      o1[i] *= alpha;
    }

    // ---- P -> own LDS chunk (same-wave DS ordering; no barrier needed)
#pragma unroll
    for (int c = 0; c < 4; ++c) {
      const uint2 s01 = splitpack2(p[4 * c + 0], p[4 * c + 1]);
      const uint2 s23 = splitpack2(p[4 * c + 2], p[4 * c + 3]);
      const int t = c >> 1, lh = c & 1;
      const int bi = (t * 64 + lh * 32 + l31) * 8 + lhi * 4;
      *(uint2*)&Pw[bi] = uint2{s01.x, s23.x};
      *(uint2*)&Pw[1024 + bi] = uint2{s01.y, s23.y};
    }

    // ---- O^T += V^T · P^T
#pragma unroll
    for (int t = 0; t < 2; ++t) {
      const bf16x8 ph = *(const bf16x8*)&Pw[(t * 64 + lane) * 8];
      const bf16x8 pl_ = *(const bf16x8*)&Pw[1024 + (t * 64 + lane) * 8];
      bf16x8 vh = *(const bf16x8*)&Vf[(((wk * 2 + 0) * 2 + t) * 64 + lane) * 8];
      bf16x8 vl =
          *(const bf16x8*)&Vf[((((2 + wk) * 2 + 0) * 2 + t) * 64 + lane) * 8];
      o0 = MFMA32(vh, ph, o0, 0, 0, 0);
      o0 = MFMA32(vh, pl_, o0, 0, 0, 0);
      o0 = MFMA32(vl, ph, o0, 0, 0, 0);
      vh = *(const bf16x8*)&Vf[(((wk * 2 + 1) * 2 + t) * 64 + lane) * 8];
      vl = *(const bf16x8*)&Vf[((((2 + wk) * 2 + 1) * 2 + t) * 64 + lane) * 8];
      o1 = MFMA32(vh, ph, o1, 0, 0, 0);
      o1 = MFMA32(vh, pl_, o1, 0, 0, 0);
      o1 = MFMA32(vl, ph, o1, 0, 0, 0);
    }

    // ---- fuse next iter's sa from prefetched regs (loads landed by now)
#pragma unroll
    for (int c = 0; c < 4; ++c) {
      sa[4 * c + 0] = (mkn[c].x != 0.f) ? hs * shn[c].x : 1e9f;
      sa[4 * c + 1] = (mkn[c].y != 0.f) ? hs * shn[c].y : 1e9f;
      sa[4 * c + 2] = (mkn[c].z != 0.f) ? hs * shn[c].z : 1e9f;
      sa[4 * c + 3] = (mkn[c].w != 0.f) ? hs * shn[c].w : 1e9f;
    }
    __syncthreads();
  }

  // ---- merge wk=0/1 (same wq) through LDS (aliases pool; post-barrier)
  float* mL = (float*)smem;  // [64]
  float* lL = mL + 64;       // [64]
  float* Om = lL + 64;       // [2][64][33]
  if (wk == 1) {
    if (lhi == 0) {
      mL[wq * 32 + l31] = m_run;
      lL[wq * 32 + l31] = l_run;
    }
#pragma unroll
    for (int mt = 0; mt < 2; ++mt)
#pragma unroll
      for (int r = 0; r < 16; ++r) {
        const int row = mt * 32 + (r & 3) + 8 * (r >> 2) + 4 * lhi;
        Om[(wq * 64 + row) * 33 + l31] = (mt ? o1[r] : o0[r]);
      }
  }
  __syncthreads();
  if (wk == 0) {
    const float m1 = mL[wq * 32 + l31];
    const float l1v = lL[wq * 32 + l31];
    const float mst = fmaxf(m_run, m1);
    const float a0 = __expf(m_run - mst), a1 = __expf(m1 - mst);
    const float inv = 1.f / (a0 * l_run + a1 * l1v);
    const int tok = b * 2048 + qg;
#pragma unroll
    for (int mt = 0; mt < 2; ++mt)
#pragma unroll
      for (int r = 0; r < 16; ++r) {
        const int row = mt * 32 + (r & 3) + 8 * (r >> 2) + 4 * lhi;
        const float val =
            (a0 * (mt ? o1[r] : o0[r]) + a1 * Om[(wq * 64 + row) * 33 + l31]) *
            inv;
        const int d = h * 64 + row;
        u16 hi, lo;
        split1(val, hi, lo);
        const size_t idx = ((size_t)(d >> 3) * 4096 + tok) * 8 + (d & 7);
        Othi[idx] = hi;
        Otlo[idx] = lo;
      }
  }
}

// ---------------------------------------------------------------------------
// GEMM2 (MFMA): out = o @ Wo^T + bo. A from Otc chunk planes (b128 staging),
// B = Wo fp32 converted inline. Tiles 64x64, BK=32, 4 waves (2x2), 1 tile ea.
// ---------------------------------------------------------------------------
__global__ __launch_bounds__(256, 2) void gemm2_mfma(
    const u16* __restrict__ Othi, const u16* __restrict__ Otlo,
    const float* __restrict__ Wo, const float* __restrict__ bo,
    float* __restrict__ out) {
  __shared__ __align__(16) u16 Af[2][2][2][64][8];  // 8 KB
  __shared__ __align__(16) u16 Bf[2][2][2][64][8];  // 8 KB
  const int tid = threadIdx.x;
  const int wave = tid >> 6, lane = tid & 63, l31 = lane & 31, lhi = lane >> 5;
  const int wm = wave >> 1, wn = wave & 1;
  const int m0 = blockIdx.y * 64, n0 = blockIdx.x * 64;

  f32x16 acc;
#pragma unroll
  for (int r = 0; r < 16; ++r) acc[r] = 0.f;

  for (int k0 = 0; k0 < 512; k0 += 32) {
#pragma unroll
    for (int i = 0; i < 2; ++i) {
      const int f = i * 256 + tid;
      const int p = f >> 8, rem = f & 255, c = rem >> 6, tok = rem & 63;
      const u16* src =
          (p ? Otlo : Othi) + ((size_t)(k0 / 8 + c) * 4096 + m0 + tok) * 8;
      *(uint4*)&Af[p][tok >> 5][c >> 1][(c & 1) * 32 + (tok & 31)][0] =
          *(const uint4*)src;
    }
    {
      const int n = tid >> 2, c = tid & 3;
      const float* src = Wo + (size_t)(n0 + n) * 512 + k0 + c * 8;
      const float4 v0 = *(const float4*)src;
      const float4 v1 = *(const float4*)(src + 4);
      const uint2 q0 = splitpack2(v0.x, v0.y), q1 = splitpack2(v0.z, v0.w);
      const uint2 q2 = splitpack2(v1.x, v1.y), q3 = splitpack2(v1.z, v1.w);
      *(uint4*)&Bf[0][n >> 5][c >> 1][(c & 1) * 32 + (n & 31)][0] =
          uint4{q0.x, q1.x, q2.x, q3.x};
      *(uint4*)&Bf[1][n >> 5][c >> 1][(c & 1) * 32 + (n & 31)][0] =
          uint4{q0.y, q1.y, q2.y, q3.y};
    }
    __syncthreads();
#pragma unroll
    for (int t = 0; t < 2; ++t) {
      const bf16x8 ah = *(const bf16x8*)&Af[0][wm][t][lane][0];
      const bf16x8 al = *(const bf16x8*)&Af[1][wm][t][lane][0];
      const bf16x8 bh = *(const bf16x8*)&Bf[0][wn][t][lane][0];
      const bf16x8 bl = *(const bf16x8*)&Bf[1][wn][t][lane][0];
      acc = MFMA32(ah, bh, acc, 0, 0, 0);
      acc = MFMA32(ah, bl, acc, 0, 0, 0);
      acc = MFMA32(al, bh, acc, 0, 0, 0);
    }
    __syncthreads();
  }

  const int n = n0 + wn * 32 + l31;
  const float bn = bo[n];
#pragma unroll
  for (int r = 0; r < 16; ++r) {
    const int m = m0 + wm * 32 + (r & 3) + 8 * (r >> 2) + 4 * lhi;
    out[(size_t)m * 512 + n] = acc[r] + bn;
  }
}

// ---------------------------------------------------------------------------
extern "C" void kernel_launch(void* const* d_in, const int* in_sizes, int n_in,
                              void* d_out, int out_size, void* d_ws,
                              size_t ws_size, hipStream_t stream) {
  const float* x = (const float*)d_in[0];
  const float* shift = (const float*)d_in[1];
  const float* mask = (const float*)d_in[2];
  const float* W = (const float*)d_in[3];
  const float* b = (const float*)d_in[4];
  const float* Wo = (const float*)d_in[5];
  const float* bo = (const float*)d_in[6];
  float* out = (float*)d_out;

  // ws (32 MiB): [0,6P) Q/K/V hi+lo planes, [6P,8P) Ot hi/lo chunk planes.
  const size_t P = (size_t)Hc * Bc * Sc * DHc;  // 2,097,152
  u16* ws0 = (u16*)d_ws;
  u16* Qhi = ws0;
  u16* Qlo = ws0 + P;
  u16* Khi = ws0 + 2 * P;
  u16* Klo = ws0 + 3 * P;
  u16* Vthi = ws0 + 4 * P;
  u16* Vtlo = ws0 + 5 * P;
  u16* Othi = ws0 + 6 * P;
  u16* Otlo = ws0 + 7 * P;

  // 1) QKV projection (MFMA, inline fp32->bf16 hi/lo split)
  gemm1_mfma<<<dim3(NQKV / 64, (Bc * Sc) / 128), 256, 0, stream>>>(
      x, W, b, Qhi, Qlo, Khi, Klo, Vthi, Vtlo);

  // 2) MFMA flash attention (register-pipelined) -> Ot chunk planes
  attn_mfma<<<dim3(Sc / 64, Bc, Hc), 256, 0, stream>>>(
      Qhi, Qlo, Khi, Klo, Vthi, Vtlo, shift, mask, Othi, Otlo);

  // 3) output projection (MFMA) -> out
  gemm2_mfma<<<dim3(Dc / 64, (Bc * Sc) / 64), 256, 0, stream>>>(Othi, Otlo, Wo,
                                                                bo, out);
}

// Round 8
// 365.972 us; speedup vs baseline: 1.1533x; 1.1533x over previous
//
#include <hip/hip_runtime.h>
#include <math.h>

// Problem constants (fixed by reference)
constexpr int Bc = 2, Sc = 2048, Dc = 512, Hc = 8, DHc = 64;
constexpr int NQKV = 3 * Dc;  // 1536

typedef unsigned short u16;
typedef unsigned int u32;
typedef __attribute__((ext_vector_type(8))) __bf16 bf16x8;
typedef __attribute__((ext_vector_type(16))) float f32x16;

#define MFMA32 __builtin_amdgcn_mfma_f32_32x32x16_bf16

// Truncation hi/lo split of two floats, packed: ret.x = (hi(b)<<16)|hi(a),
// ret.y = lo-pair. hi = truncate-to-bf16; lo = bf16(residual).
__device__ inline uint2 splitpack2(float a, float b) {
  u32 ua = __float_as_uint(a), ub = __float_as_uint(b);
  u32 hi = (ub & 0xFFFF0000u) | (ua >> 16);
  float ra = a - __uint_as_float(ua & 0xFFFF0000u);
  float rb = b - __uint_as_float(ub & 0xFFFF0000u);
  u32 lo = (__float_as_uint(rb) & 0xFFFF0000u) | (__float_as_uint(ra) >> 16);
  return uint2{hi, lo};
}
__device__ inline void split1(float v, u16& hi, u16& lo) {
  u32 u = __float_as_uint(v);
  hi = (u16)(u >> 16);
  float r = v - __uint_as_float(u & 0xFFFF0000u);
  lo = (u16)(__float_as_uint(r) >> 16);
}

// ---------------------------------------------------------------------------
// GEMM1 (MFMA): qkv = x @ W^T + b, fp32 inputs split to bf16 hi/lo inline
// during staging. Tiles 128x64, BK=32, 4 waves (2x2), 2 m-tiles per wave.
// Epilogue splits to Q/K [h][b][s][dh] and V^T [h][b][dh][s] bf16 planes.
// Q is pre-scaled by 0.125 (folds the 1/sqrt(DH) logit scale).
// ---------------------------------------------------------------------------
__global__ __launch_bounds__(256, 2) void gemm1_mfma(
    const float* __restrict__ x, const float* __restrict__ W,
    const float* __restrict__ bias, u16* __restrict__ Qhi,
    u16* __restrict__ Qlo, u16* __restrict__ Khi, u16* __restrict__ Klo,
    u16* __restrict__ Vthi, u16* __restrict__ Vtlo) {
  __shared__ __align__(16) u16 Af[2][4][2][64][8];  // 16 KB
  __shared__ __align__(16) u16 Bf[2][2][2][64][8];  // 8 KB
  const int tid = threadIdx.x;
  const int wave = tid >> 6, lane = tid & 63, l31 = lane & 31, lhi = lane >> 5;
  const int wm = wave >> 1, wn = wave & 1;
  const int m0 = blockIdx.y * 128, n0 = blockIdx.x * 64;

  f32x16 acc[2];
#pragma unroll
  for (int r = 0; r < 16; ++r) {
    acc[0][r] = 0.f;
    acc[1][r] = 0.f;
  }

  for (int k0 = 0; k0 < 512; k0 += 32) {
    // stage A: 512 8-elem k-groups (128 m x 4), 2 per thread, split inline
#pragma unroll
    for (int i = 0; i < 2; ++i) {
      const int g = i * 256 + tid;
      const int m = g >> 2, kg = g & 3;
      const float* src = x + (size_t)(m0 + m) * 512 + k0 + kg * 8;
      const float4 v0 = *(const float4*)src;
      const float4 v1 = *(const float4*)(src + 4);
      const uint2 p0 = splitpack2(v0.x, v0.y), p1 = splitpack2(v0.z, v0.w);
      const uint2 p2 = splitpack2(v1.x, v1.y), p3 = splitpack2(v1.z, v1.w);
      *(uint4*)&Af[0][m >> 5][kg >> 1][(kg & 1) * 32 + (m & 31)][0] =
          uint4{p0.x, p1.x, p2.x, p3.x};
      *(uint4*)&Af[1][m >> 5][kg >> 1][(kg & 1) * 32 + (m & 31)][0] =
          uint4{p0.y, p1.y, p2.y, p3.y};
    }
    // stage B: 256 groups, 1 per thread
    {
      const int n = tid >> 2, kg = tid & 3;
      const float* src = W + (size_t)(n0 + n) * 512 + k0 + kg * 8;
      const float4 v0 = *(const float4*)src;
      const float4 v1 = *(const float4*)(src + 4);
      const uint2 p0 = splitpack2(v0.x, v0.y), p1 = splitpack2(v0.z, v0.w);
      const uint2 p2 = splitpack2(v1.x, v1.y), p3 = splitpack2(v1.z, v1.w);
      *(uint4*)&Bf[0][n >> 5][kg >> 1][(kg & 1) * 32 + (n & 31)][0] =
          uint4{p0.x, p1.x, p2.x, p3.x};
      *(uint4*)&Bf[1][n >> 5][kg >> 1][(kg & 1) * 32 + (n & 31)][0] =
          uint4{p0.y, p1.y, p2.y, p3.y};
    }
    __syncthreads();
#pragma unroll
    for (int t = 0; t < 2; ++t) {
      const bf16x8 bh = *(const bf16x8*)&Bf[0][wn][t][lane][0];
      const bf16x8 bl = *(const bf16x8*)&Bf[1][wn][t][lane][0];
#pragma unroll
      for (int ti = 0; ti < 2; ++ti) {
        const bf16x8 ah = *(const bf16x8*)&Af[0][wm * 2 + ti][t][lane][0];
        const bf16x8 al = *(const bf16x8*)&Af[1][wm * 2 + ti][t][lane][0];
        acc[ti] = MFMA32(ah, bh, acc[ti], 0, 0, 0);
        acc[ti] = MFMA32(ah, bl, acc[ti], 0, 0, 0);
        acc[ti] = MFMA32(al, bh, acc[ti], 0, 0, 0);
      }
    }
    __syncthreads();
  }

  // epilogue: C col (lane&31) = n, rows per reg. t3 uniform per wave.
  const int n = n0 + wn * 32 + l31;
  const float bn = bias[n];
  const int h = n / 192, rem = n - h * 192, t3 = rem >> 6, dh = rem & 63;
#pragma unroll
  for (int ti = 0; ti < 2; ++ti)
#pragma unroll
    for (int r = 0; r < 16; ++r) {
      const int m = m0 + wm * 64 + ti * 32 + (r & 3) + 8 * (r >> 2) + 4 * lhi;
      const int batch = m >> 11, s = m & 2047;
      float val = acc[ti][r] + bn;
      if (t3 == 0) val *= 0.125f;  // fold logit scale into Q
      u16 hi, lo;
      split1(val, hi, lo);
      const int hbq = h * 2 + batch;
      if (t3 == 2) {
        const size_t idx = ((size_t)hbq * 64 + dh) * 2048 + s;
        Vthi[idx] = hi;
        Vtlo[idx] = lo;
      } else {
        const size_t idx = ((size_t)hbq * 2048 + s) * 64 + dh;
        if (t3 == 0) {
          Qhi[idx] = hi;
          Qlo[idx] = lo;
        } else {
          Khi[idx] = hi;
          Klo[idx] = lo;
        }
      }
    }
}

// ---------------------------------------------------------------------------
// MFMA flash attention, R8: BARRIER-FREE K-loop. K and V fragments are loaded
// directly global->registers (A-operand layout m=lane&31, k=(lane>>5)*8+j maps
// to clean 16B/lane loads from the K / V^T planes). No K/V LDS staging, no
// per-iter __syncthreads, no cross-iter register state (R7 spill trap).
// P round-trips through wave-private LDS (same-wave DS ordering, no barrier).
// Load issue order K -> V -> SM so per-use vmcnt waits don't serialize on the
// slow SM stream. One barrier total (before merge-region overlay).
// Block = 4 waves = (wq 0..1) x (wk 0..1); 64 q rows per block. LDS ~17 KB.
// ---------------------------------------------------------------------------
__global__ __launch_bounds__(256, 2) void attn_mfma(
    const u16* __restrict__ Qhi, const u16* __restrict__ Qlo,
    const u16* __restrict__ Khi, const u16* __restrict__ Klo,
    const u16* __restrict__ Vthi, const u16* __restrict__ Vtlo,
    const float* __restrict__ shift, const float* __restrict__ mask,
    u16* __restrict__ Othi, u16* __restrict__ Otlo) {
  const int h = blockIdx.z, b = blockIdx.y;
  const int qb = blockIdx.x;
  const int tid = threadIdx.x;
  const int wave = tid >> 6;
  const int wq = wave >> 1, wk = wave & 1;
  const int lane = tid & 63;
  const int l31 = lane & 31, lhi = lane >> 5;

  // 17.4 KB pool: P chunks [wave][t2][64][8] u16 hi + lo (16 KB), overlaid by
  // the fp32 merge region after the post-loop barrier.
  __shared__ __align__(16) u16 smem[8704];
  u16* Pw = smem + wave * 2048;  // this wave's chunk: hi [0,1024), lo [1024,2048)

  const size_t hb = (size_t)h * Bc + b;
  const int ql = wq * 32 + l31;  // q within block tile
  const int qg = qb * 64 + ql;   // global q

  // Q B-frags (pre-scaled by 0.125): n=q, k = t*16 + lhi*8 + j
  bf16x8 qf[2][4];
  {
    const size_t qbase = (hb * Sc + qg) * DHc;
#pragma unroll
    for (int t = 0; t < 4; ++t) {
      qf[0][t] = *(const bf16x8*)(Qhi + qbase + t * 16 + lhi * 8);
      qf[1][t] = *(const bf16x8*)(Qlo + qbase + t * 16 + lhi * 8);
    }
  }
  const float hs = exp2f(-(float)h);

  // per-lane SM row bases; per-iter key offset = it*64 (+ wk*32 + lhi*4 baked)
  const float* shrow = shift + ((size_t)b * Sc + qg) * Sc + wk * 32 + lhi * 4;
  const float* mkrow = mask + ((size_t)b * Sc + qg) * Sc + wk * 32 + lhi * 4;

  // K frag base: row = key (l31), 16B chunk at t*16 + lhi*8
  const u16* kbase_h = Khi + (hb * Sc + wk * 32 + l31) * 64 + lhi * 8;
  const u16* kbase_l = Klo + (hb * Sc + wk * 32 + l31) * 64 + lhi * 8;
  // V frag bases: row = dh (l31 / 32+l31), col = key
  const u16* vbase0_h = Vthi + (hb * 64 + l31) * 2048 + wk * 32 + lhi * 8;
  const u16* vbase0_l = Vtlo + (hb * 64 + l31) * 2048 + wk * 32 + lhi * 8;
  const u16* vbase1_h = vbase0_h + 32 * 2048;
  const u16* vbase1_l = vbase0_l + 32 * 2048;

  float m_run = -INFINITY, l_run = 0.f;
  f32x16 o0, o1;
#pragma unroll
  for (int i = 0; i < 16; ++i) {
    o0[i] = 0.f;
    o1[i] = 0.f;
  }

  for (int it = 0; it < 32; ++it) {
    const int ko = it * 64;  // key offset of this iter (element units)

    // ---- issue loads: K (oldest), V, SM (newest)
    bf16x8 kh[4], kl[4];
#pragma unroll
    for (int t = 0; t < 4; ++t) {
      kh[t] = *(const bf16x8*)(kbase_h + (size_t)ko * 64 + t * 16);
      kl[t] = *(const bf16x8*)(kbase_l + (size_t)ko * 64 + t * 16);
    }
    bf16x8 vh0[2], vl0[2], vh1[2], vl1[2];
#pragma unroll
    for (int t = 0; t < 2; ++t) {
      vh0[t] = *(const bf16x8*)(vbase0_h + ko + t * 16);
      vl0[t] = *(const bf16x8*)(vbase0_l + ko + t * 16);
      vh1[t] = *(const bf16x8*)(vbase1_h + ko + t * 16);
      vl1[t] = *(const bf16x8*)(vbase1_l + ko + t * 16);
    }
    float4 s4[4], m4[4];
#pragma unroll
    for (int c = 0; c < 4; ++c) {
      s4[c] = *(const float4*)(shrow + ko + c * 8);
      m4[c] = *(const float4*)(mkrow + ko + c * 8);
    }

    // ---- S^T = K·Q^T (m=key, n=q): Khi*Qhi + Khi*Qlo + Klo*Qhi
    f32x16 s;
#pragma unroll
    for (int i = 0; i < 16; ++i) s[i] = 0.f;
#pragma unroll
    for (int t = 0; t < 4; ++t) {
      s = MFMA32(kh[t], qf[0][t], s, 0, 0, 0);
      s = MFMA32(kh[t], qf[1][t], s, 0, 0, 0);
      s = MFMA32(kl[t], qf[0][t], s, 0, 0, 0);
    }

    // ---- fuse sa + logits + online softmax (q = lane col)
    float p[16];
    float kmax = -INFINITY;
#pragma unroll
    for (int c = 0; c < 4; ++c) {
      const float sv[4] = {s4[c].x, s4[c].y, s4[c].z, s4[c].w};
      const float mv[4] = {m4[c].x, m4[c].y, m4[c].z, m4[c].w};
#pragma unroll
      for (int e = 0; e < 4; ++e) {
        const float a = (mv[e] != 0.f) ? hs * sv[e] : 1e9f;
        const float lg = s[4 * c + e] - a;
        p[4 * c + e] = lg;
        kmax = fmaxf(kmax, lg);
      }
    }
    kmax = fmaxf(kmax, __shfl_xor(kmax, 32, 64));
    const float mnew = fmaxf(m_run, kmax);
    const float alpha = __expf(m_run - mnew);
    float rsum = 0.f;
#pragma unroll
    for (int r = 0; r < 16; ++r) {
      p[r] = __expf(p[r] - mnew);
      rsum += p[r];
    }
    rsum += __shfl_xor(rsum, 32, 64);
    l_run = l_run * alpha + rsum;
    m_run = mnew;
#pragma unroll
    for (int i = 0; i < 16; ++i) {
      o0[i] *= alpha;
      o1[i] *= alpha;
    }

    // ---- P -> own LDS chunk (same-wave DS ordering; no barrier needed)
#pragma unroll
    for (int c = 0; c < 4; ++c) {
      const uint2 s01 = splitpack2(p[4 * c + 0], p[4 * c + 1]);
      const uint2 s23 = splitpack2(p[4 * c + 2], p[4 * c + 3]);
      const int t = c >> 1, lh = c & 1;
      const int bi = (t * 64 + lh * 32 + l31) * 8 + lhi * 4;
      *(uint2*)&Pw[bi] = uint2{s01.x, s23.x};
      *(uint2*)&Pw[1024 + bi] = uint2{s01.y, s23.y};
    }

    // ---- O^T += V^T · P^T
#pragma unroll
    for (int t = 0; t < 2; ++t) {
      const bf16x8 ph = *(const bf16x8*)&Pw[(t * 64 + lane) * 8];
      const bf16x8 pl_ = *(const bf16x8*)&Pw[1024 + (t * 64 + lane) * 8];
      o0 = MFMA32(vh0[t], ph, o0, 0, 0, 0);
      o0 = MFMA32(vh0[t], pl_, o0, 0, 0, 0);
      o0 = MFMA32(vl0[t], ph, o0, 0, 0, 0);
      o1 = MFMA32(vh1[t], ph, o1, 0, 0, 0);
      o1 = MFMA32(vh1[t], pl_, o1, 0, 0, 0);
      o1 = MFMA32(vl1[t], ph, o1, 0, 0, 0);
    }
  }

  __syncthreads();  // all P-chunk traffic done before merge-region overlay

  // ---- merge wk=0/1 (same wq) through LDS (aliases P pool; post-barrier)
  float* mL = (float*)smem;  // [64]
  float* lL = mL + 64;       // [64]
  float* Om = lL + 64;       // [2][64][33]
  if (wk == 1) {
    if (lhi == 0) {
      mL[wq * 32 + l31] = m_run;
      lL[wq * 32 + l31] = l_run;
    }
#pragma unroll
    for (int mt = 0; mt < 2; ++mt)
#pragma unroll
      for (int r = 0; r < 16; ++r) {
        const int row = mt * 32 + (r & 3) + 8 * (r >> 2) + 4 * lhi;
        Om[(wq * 64 + row) * 33 + l31] = (mt ? o1[r] : o0[r]);
      }
  }
  __syncthreads();
  if (wk == 0) {
    const float m1 = mL[wq * 32 + l31];
    const float l1v = lL[wq * 32 + l31];
    const float mst = fmaxf(m_run, m1);
    const float a0 = __expf(m_run - mst), a1 = __expf(m1 - mst);
    const float inv = 1.f / (a0 * l_run + a1 * l1v);
    const int tok = b * 2048 + qg;
#pragma unroll
    for (int mt = 0; mt < 2; ++mt)
#pragma unroll
      for (int r = 0; r < 16; ++r) {
        const int row = mt * 32 + (r & 3) + 8 * (r >> 2) + 4 * lhi;
        const float val =
            (a0 * (mt ? o1[r] : o0[r]) + a1 * Om[(wq * 64 + row) * 33 + l31]) *
            inv;
        const int d = h * 64 + row;
        u16 hi, lo;
        split1(val, hi, lo);
        const size_t idx = ((size_t)(d >> 3) * 4096 + tok) * 8 + (d & 7);
        Othi[idx] = hi;
        Otlo[idx] = lo;
      }
  }
}

// ---------------------------------------------------------------------------
// GEMM2 (MFMA): out = o @ Wo^T + bo. A from Otc chunk planes (b128 staging),
// B = Wo fp32 converted inline. Tiles 64x64, BK=32, 4 waves (2x2), 1 tile ea.
// ---------------------------------------------------------------------------
__global__ __launch_bounds__(256, 2) void gemm2_mfma(
    const u16* __restrict__ Othi, const u16* __restrict__ Otlo,
    const float* __restrict__ Wo, const float* __restrict__ bo,
    float* __restrict__ out) {
  __shared__ __align__(16) u16 Af[2][2][2][64][8];  // 8 KB
  __shared__ __align__(16) u16 Bf[2][2][2][64][8];  // 8 KB
  const int tid = threadIdx.x;
  const int wave = tid >> 6, lane = tid & 63, l31 = lane & 31, lhi = lane >> 5;
  const int wm = wave >> 1, wn = wave & 1;
  const int m0 = blockIdx.y * 64, n0 = blockIdx.x * 64;

  f32x16 acc;
#pragma unroll
  for (int r = 0; r < 16; ++r) acc[r] = 0.f;

  for (int k0 = 0; k0 < 512; k0 += 32) {
#pragma unroll
    for (int i = 0; i < 2; ++i) {
      const int f = i * 256 + tid;
      const int p = f >> 8, rem = f & 255, c = rem >> 6, tok = rem & 63;
      const u16* src =
          (p ? Otlo : Othi) + ((size_t)(k0 / 8 + c) * 4096 + m0 + tok) * 8;
      *(uint4*)&Af[p][tok >> 5][c >> 1][(c & 1) * 32 + (tok & 31)][0] =
          *(const uint4*)src;
    }
    {
      const int n = tid >> 2, c = tid & 3;
      const float* src = Wo + (size_t)(n0 + n) * 512 + k0 + c * 8;
      const float4 v0 = *(const float4*)src;
      const float4 v1 = *(const float4*)(src + 4);
      const uint2 q0 = splitpack2(v0.x, v0.y), q1 = splitpack2(v0.z, v0.w);
      const uint2 q2 = splitpack2(v1.x, v1.y), q3 = splitpack2(v1.z, v1.w);
      *(uint4*)&Bf[0][n >> 5][c >> 1][(c & 1) * 32 + (n & 31)][0] =
          uint4{q0.x, q1.x, q2.x, q3.x};
      *(uint4*)&Bf[1][n >> 5][c >> 1][(c & 1) * 32 + (n & 31)][0] =
          uint4{q0.y, q1.y, q2.y, q3.y};
    }
    __syncthreads();
#pragma unroll
    for (int t = 0; t < 2; ++t) {
      const bf16x8 ah = *(const bf16x8*)&Af[0][wm][t][lane][0];
      const bf16x8 al = *(const bf16x8*)&Af[1][wm][t][lane][0];
      const bf16x8 bh = *(const bf16x8*)&Bf[0][wn][t][lane][0];
      const bf16x8 bl = *(const bf16x8*)&Bf[1][wn][t][lane][0];
      acc = MFMA32(ah, bh, acc, 0, 0, 0);
      acc = MFMA32(ah, bl, acc, 0, 0, 0);
      acc = MFMA32(al, bh, acc, 0, 0, 0);
    }
    __syncthreads();
  }

  const int n = n0 + wn * 32 + l31;
  const float bn = bo[n];
#pragma unroll
  for (int r = 0; r < 16; ++r) {
    const int m = m0 + wm * 32 + (r & 3) + 8 * (r >> 2) + 4 * lhi;
    out[(size_t)m * 512 + n] = acc[r] + bn;
  }
}

// ---------------------------------------------------------------------------
extern "C" void kernel_launch(void* const* d_in, const int* in_sizes, int n_in,
                              void* d_out, int out_size, void* d_ws,
                              size_t ws_size, hipStream_t stream) {
  const float* x = (const float*)d_in[0];
  const float* shift = (const float*)d_in[1];
  const float* mask = (const float*)d_in[2];
  const float* W = (const float*)d_in[3];
  const float* b = (const float*)d_in[4];
  const float* Wo = (const float*)d_in[5];
  const float* bo = (const float*)d_in[6];
  float* out = (float*)d_out;

  // ws (32 MiB): [0,6P) Q/K/V hi+lo planes, [6P,8P) Ot hi/lo chunk planes.
  const size_t P = (size_t)Hc * Bc * Sc * DHc;  // 2,097,152
  u16* ws0 = (u16*)d_ws;
  u16* Qhi = ws0;
  u16* Qlo = ws0 + P;
  u16* Khi = ws0 + 2 * P;
  u16* Klo = ws0 + 3 * P;
  u16* Vthi = ws0 + 4 * P;
  u16* Vtlo = ws0 + 5 * P;
  u16* Othi = ws0 + 6 * P;
  u16* Otlo = ws0 + 7 * P;

  // 1) QKV projection (MFMA, inline fp32->bf16 hi/lo split; Q pre-scaled)
  gemm1_mfma<<<dim3(NQKV / 64, (Bc * Sc) / 128), 256, 0, stream>>>(
      x, W, b, Qhi, Qlo, Khi, Klo, Vthi, Vtlo);

  // 2) MFMA flash attention (barrier-free K-loop) -> Ot chunk planes
  attn_mfma<<<dim3(Sc / 64, Bc, Hc), 256, 0, stream>>>(
      Qhi, Qlo, Khi, Klo, Vthi, Vtlo, shift, mask, Othi, Otlo);

  // 3) output projection (MFMA) -> out
  gemm2_mfma<<<dim3(Dc / 64, (Bc * Sc) / 64), 256, 0, stream>>>(Othi, Otlo, Wo,
                                                                bo, out);
}

// Round 9
// 298.706 us; speedup vs baseline: 1.4130x; 1.2252x over previous
//
#include <hip/hip_runtime.h>
#include <math.h>

// Problem constants (fixed by reference)
constexpr int Bc = 2, Sc = 2048, Dc = 512, Hc = 8, DHc = 64;
constexpr int NQKV = 3 * Dc;  // 1536

typedef unsigned short u16;
typedef unsigned int u32;
typedef __attribute__((ext_vector_type(8))) __bf16 bf16x8;
typedef __attribute__((ext_vector_type(16))) float f32x16;

#define MFMA32 __builtin_amdgcn_mfma_f32_32x32x16_bf16

// Truncation hi/lo split of two floats, packed: ret.x = (hi(b)<<16)|hi(a),
// ret.y = lo-pair. hi = truncate-to-bf16; lo = bf16(residual).
__device__ inline uint2 splitpack2(float a, float b) {
  u32 ua = __float_as_uint(a), ub = __float_as_uint(b);
  u32 hi = (ub & 0xFFFF0000u) | (ua >> 16);
  float ra = a - __uint_as_float(ua & 0xFFFF0000u);
  float rb = b - __uint_as_float(ub & 0xFFFF0000u);
  u32 lo = (__float_as_uint(rb) & 0xFFFF0000u) | (__float_as_uint(ra) >> 16);
  return uint2{hi, lo};
}
__device__ inline void split1(float v, u16& hi, u16& lo) {
  u32 u = __float_as_uint(v);
  hi = (u16)(u >> 16);
  float r = v - __uint_as_float(u & 0xFFFF0000u);
  lo = (u16)(__float_as_uint(r) >> 16);
}

// ---------------------------------------------------------------------------
// GEMM1 (MFMA): qkv = x @ W^T + b, fp32 inputs split to bf16 hi/lo inline
// during staging. Tiles 128x64, BK=32, 4 waves (2x2), 2 m-tiles per wave.
// Epilogue splits to Q/K [h][b][s][dh] and V^T [h][b][dh][s] bf16 planes.
// Q is pre-scaled by 0.125 (folds the 1/sqrt(DH) logit scale).
// ---------------------------------------------------------------------------
__global__ __launch_bounds__(256, 2) void gemm1_mfma(
    const float* __restrict__ x, const float* __restrict__ W,
    const float* __restrict__ bias, u16* __restrict__ Qhi,
    u16* __restrict__ Qlo, u16* __restrict__ Khi, u16* __restrict__ Klo,
    u16* __restrict__ Vthi, u16* __restrict__ Vtlo) {
  __shared__ __align__(16) u16 Af[2][4][2][64][8];  // 16 KB
  __shared__ __align__(16) u16 Bf[2][2][2][64][8];  // 8 KB
  const int tid = threadIdx.x;
  const int wave = tid >> 6, lane = tid & 63, l31 = lane & 31, lhi = lane >> 5;
  const int wm = wave >> 1, wn = wave & 1;
  const int m0 = blockIdx.y * 128, n0 = blockIdx.x * 64;

  f32x16 acc[2];
#pragma unroll
  for (int r = 0; r < 16; ++r) {
    acc[0][r] = 0.f;
    acc[1][r] = 0.f;
  }

  for (int k0 = 0; k0 < 512; k0 += 32) {
    // stage A: 512 8-elem k-groups (128 m x 4), 2 per thread, split inline
#pragma unroll
    for (int i = 0; i < 2; ++i) {
      const int g = i * 256 + tid;
      const int m = g >> 2, kg = g & 3;
      const float* src = x + (size_t)(m0 + m) * 512 + k0 + kg * 8;
      const float4 v0 = *(const float4*)src;
      const float4 v1 = *(const float4*)(src + 4);
      const uint2 p0 = splitpack2(v0.x, v0.y), p1 = splitpack2(v0.z, v0.w);
      const uint2 p2 = splitpack2(v1.x, v1.y), p3 = splitpack2(v1.z, v1.w);
      *(uint4*)&Af[0][m >> 5][kg >> 1][(kg & 1) * 32 + (m & 31)][0] =
          uint4{p0.x, p1.x, p2.x, p3.x};
      *(uint4*)&Af[1][m >> 5][kg >> 1][(kg & 1) * 32 + (m & 31)][0] =
          uint4{p0.y, p1.y, p2.y, p3.y};
    }
    // stage B: 256 groups, 1 per thread
    {
      const int n = tid >> 2, kg = tid & 3;
      const float* src = W + (size_t)(n0 + n) * 512 + k0 + kg * 8;
      const float4 v0 = *(const float4*)src;
      const float4 v1 = *(const float4*)(src + 4);
      const uint2 p0 = splitpack2(v0.x, v0.y), p1 = splitpack2(v0.z, v0.w);
      const uint2 p2 = splitpack2(v1.x, v1.y), p3 = splitpack2(v1.z, v1.w);
      *(uint4*)&Bf[0][n >> 5][kg >> 1][(kg & 1) * 32 + (n & 31)][0] =
          uint4{p0.x, p1.x, p2.x, p3.x};
      *(uint4*)&Bf[1][n >> 5][kg >> 1][(kg & 1) * 32 + (n & 31)][0] =
          uint4{p0.y, p1.y, p2.y, p3.y};
    }
    __syncthreads();
#pragma unroll
    for (int t = 0; t < 2; ++t) {
      const bf16x8 bh = *(const bf16x8*)&Bf[0][wn][t][lane][0];
      const bf16x8 bl = *(const bf16x8*)&Bf[1][wn][t][lane][0];
#pragma unroll
      for (int ti = 0; ti < 2; ++ti) {
        const bf16x8 ah = *(const bf16x8*)&Af[0][wm * 2 + ti][t][lane][0];
        const bf16x8 al = *(const bf16x8*)&Af[1][wm * 2 + ti][t][lane][0];
        acc[ti] = MFMA32(ah, bh, acc[ti], 0, 0, 0);
        acc[ti] = MFMA32(ah, bl, acc[ti], 0, 0, 0);
        acc[ti] = MFMA32(al, bh, acc[ti], 0, 0, 0);
      }
    }
    __syncthreads();
  }

  // epilogue: C col (lane&31) = n, rows per reg. t3 uniform per wave.
  const int n = n0 + wn * 32 + l31;
  const float bn = bias[n];
  const int h = n / 192, rem = n - h * 192, t3 = rem >> 6, dh = rem & 63;
#pragma unroll
  for (int ti = 0; ti < 2; ++ti)
#pragma unroll
    for (int r = 0; r < 16; ++r) {
      const int m = m0 + wm * 64 + ti * 32 + (r & 3) + 8 * (r >> 2) + 4 * lhi;
      const int batch = m >> 11, s = m & 2047;
      float val = acc[ti][r] + bn;
      if (t3 == 0) val *= 0.125f;  // fold logit scale into Q
      u16 hi, lo;
      split1(val, hi, lo);
      const int hbq = h * 2 + batch;
      if (t3 == 2) {
        const size_t idx = ((size_t)hbq * 64 + dh) * 2048 + s;
        Vthi[idx] = hi;
        Vtlo[idx] = lo;
      } else {
        const size_t idx = ((size_t)hbq * 2048 + s) * 64 + dh;
        if (t3 == 0) {
          Qhi[idx] = hi;
          Qlo[idx] = lo;
        } else {
          Khi[idx] = hi;
          Klo[idx] = lo;
        }
      }
    }
}

// ---------------------------------------------------------------------------
// MFMA flash attention, R9: 512-thread block = 8 waves = (hsel,wq,wk) handles
// TWO heads x 64 q. All global->LDS staging is fully coalesced (full-line
// consumption): fused SM tile (mask?shift:1e13, fp32, stored transposed
// [k][q] pad-65 -> conflict-free per-lane reads) shared by both heads; K/V
// staged per (head, wk half) by dedicated waves. Fixes R8's L1-transaction
// bound (strided frag loads) and halves SM logical traffic.
// LDS ~113 KB -> 1 block/CU (8 waves). 2 barriers/iter.
// ---------------------------------------------------------------------------
constexpr int SMF = 0;                      // SMs: fp32 [64k][65] (16640 B)
constexpr int KF0 = 8320;                   // u16 idx; Kf 16384 u16 (32 KB)
constexpr int VF0 = 24704;                  // Vf 16384 u16 (32 KB)
constexpr int PF0 = 41088;                  // Pf 16384 u16 (32 KB)

__global__ __launch_bounds__(512, 1) void attn_mfma(
    const u16* __restrict__ Qhi, const u16* __restrict__ Qlo,
    const u16* __restrict__ Khi, const u16* __restrict__ Klo,
    const u16* __restrict__ Vthi, const u16* __restrict__ Vtlo,
    const float* __restrict__ shift, const float* __restrict__ mask,
    u16* __restrict__ Othi, u16* __restrict__ Otlo) {
  const int hp = blockIdx.z, b = blockIdx.y, qb = blockIdx.x;
  const int tid = threadIdx.x;
  const int wave = tid >> 6;
  const int hsel = wave >> 2, wq = (wave >> 1) & 1, wk = wave & 1;
  const int lane = tid & 63;
  const int l31 = lane & 31, lhi = lane >> 5;

  __shared__ __align__(16) u16 smem[57472];  // 114944 B
  float* SMs = (float*)smem;                  // [64][65] transposed [k][q]
  u16* Pw = smem + PF0 + wave * 2048;         // wave P chunk: hi | lo+1024

  const int head = hp * 2 + hsel;
  const size_t hb = (size_t)head * Bc + b;
  const int ql = wq * 32 + l31;
  const int qg = qb * 64 + ql;

  // Q B-frags (pre-scaled): n=q, k = t*16 + lhi*8 + j
  bf16x8 qf[2][4];
  {
    const size_t qbase = (hb * Sc + qg) * DHc;
#pragma unroll
    for (int t = 0; t < 4; ++t) {
      qf[0][t] = *(const bf16x8*)(Qhi + qbase + t * 16 + lhi * 8);
      qf[1][t] = *(const bf16x8*)(Qlo + qbase + t * 16 + lhi * 8);
    }
  }
  const float hs = exp2f(-(float)head);

  // SM staging map: thread -> row q = tid>>3, cols (tid&7)*8 .. +7
  const int smq = tid >> 3, smk = (tid & 7) * 8;
  const float* shr = shift + ((size_t)b * Sc + qb * 64 + smq) * Sc + smk;
  const float* mkr = mask + ((size_t)b * Sc + qb * 64 + smq) * Sc + smk;

  // K staging (waves wq==0): 32 keys x 64 dh for head hsel, half wk
  const int kr = lane >> 1, kh2 = lane & 1;
  const size_t kfix = (hb * Sc + wk * 32 + kr) * 64 + kh2 * 32;
  // V staging (waves wq==1): lane = dh row
  const size_t vfix = (hb * 64 + lane) * 2048 + wk * 32;
  const int vmt = lane >> 5, vdl = lane & 31;

  float m_run = -INFINITY, l_run = 0.f;
  f32x16 o0, o1;
#pragma unroll
  for (int i = 0; i < 16; ++i) {
    o0[i] = 0.f;
    o1[i] = 0.f;
  }

  for (int it = 0; it < 32; ++it) {
    const int kt = it * 64;
    // ---- stage SM (all 512 threads): 2x(shift,mask) float4, fuse, store
    {
      const float4 s0 = *(const float4*)(shr + kt);
      const float4 s1 = *(const float4*)(shr + kt + 4);
      const float4 m0 = *(const float4*)(mkr + kt);
      const float4 m1 = *(const float4*)(mkr + kt + 4);
      float* dst = SMs + (size_t)smk * 65 + smq;
      dst[0 * 65] = (m0.x != 0.f) ? s0.x : 1e13f;
      dst[1 * 65] = (m0.y != 0.f) ? s0.y : 1e13f;
      dst[2 * 65] = (m0.z != 0.f) ? s0.z : 1e13f;
      dst[3 * 65] = (m0.w != 0.f) ? s0.w : 1e13f;
      dst[4 * 65] = (m1.x != 0.f) ? s1.x : 1e13f;
      dst[5 * 65] = (m1.y != 0.f) ? s1.y : 1e13f;
      dst[6 * 65] = (m1.z != 0.f) ? s1.z : 1e13f;
      dst[7 * 65] = (m1.w != 0.f) ? s1.w : 1e13f;
    }
    // ---- stage K (wq==0) / V^T (wq==1) for head hsel, half wk
    if (wq == 0) {
      const size_t gb = kfix + (size_t)kt * 64;
#pragma unroll
      for (int c = 0; c < 4; ++c) {
        const int dhc = kh2 * 32 + c * 8;
        const int t = dhc >> 4, lh = (dhc >> 3) & 1;
        *(uint4*)&smem[KF0 + ((((hsel * 2 + 0) * 2 + wk) * 4 + t) * 64 +
                              lh * 32 + kr) * 8] =
            *(const uint4*)(Khi + gb + c * 8);
        *(uint4*)&smem[KF0 + ((((hsel * 2 + 1) * 2 + wk) * 4 + t) * 64 +
                              lh * 32 + kr) * 8] =
            *(const uint4*)(Klo + gb + c * 8);
      }
    } else {
      const size_t gb = vfix + kt;
#pragma unroll
      for (int c = 0; c < 4; ++c) {
        const int t = c >> 1, lh = c & 1;
        *(uint4*)&smem[VF0 + (((((hsel * 2 + 0) * 2 + wk) * 2 + vmt) * 2 + t) *
                                  64 + lh * 32 + vdl) * 8] =
            *(const uint4*)(Vthi + gb + c * 8);
        *(uint4*)&smem[VF0 + (((((hsel * 2 + 1) * 2 + wk) * 2 + vmt) * 2 + t) *
                                  64 + lh * 32 + vdl) * 8] =
            *(const uint4*)(Vtlo + gb + c * 8);
      }
    }
    __syncthreads();

    // ---- S^T = K·Q^T (m=key32, n=q32): Khi*Qhi + Khi*Qlo + Klo*Qhi
    f32x16 s;
#pragma unroll
    for (int i = 0; i < 16; ++i) s[i] = 0.f;
#pragma unroll
    for (int t = 0; t < 4; ++t) {
      const bf16x8 kh = *(const bf16x8*)&smem[KF0 +
          ((((hsel * 2 + 0) * 2 + wk) * 4 + t) * 64 + lane) * 8];
      const bf16x8 kl = *(const bf16x8*)&smem[KF0 +
          ((((hsel * 2 + 1) * 2 + wk) * 4 + t) * 64 + lane) * 8];
      s = MFMA32(kh, qf[0][t], s, 0, 0, 0);
      s = MFMA32(kh, qf[1][t], s, 0, 0, 0);
      s = MFMA32(kl, qf[0][t], s, 0, 0, 0);
    }

    // ---- logits from SMs (conflict-free: lane l31 = q consecutive) + softmax
    float p[16];
    float kmax = -INFINITY;
#pragma unroll
    for (int c = 0; c < 4; ++c) {
#pragma unroll
      for (int e = 0; e < 4; ++e) {
        const int kl_ = wk * 32 + c * 8 + lhi * 4 + e;
        const float a = hs * SMs[(size_t)kl_ * 65 + ql];
        const float lg = s[4 * c + e] - a;
        p[4 * c + e] = lg;
        kmax = fmaxf(kmax, lg);
      }
    }
    kmax = fmaxf(kmax, __shfl_xor(kmax, 32, 64));
    const float mnew = fmaxf(m_run, kmax);
    const float alpha = __expf(m_run - mnew);
    float rsum = 0.f;
#pragma unroll
    for (int r = 0; r < 16; ++r) {
      p[r] = __expf(p[r] - mnew);
      rsum += p[r];
    }
    rsum += __shfl_xor(rsum, 32, 64);
    l_run = l_run * alpha + rsum;
    m_run = mnew;
#pragma unroll
    for (int i = 0; i < 16; ++i) {
      o0[i] *= alpha;
      o1[i] *= alpha;
    }

    // ---- P -> own LDS chunk (same-wave DS ordering; no barrier needed)
#pragma unroll
    for (int c = 0; c < 4; ++c) {
      const uint2 s01 = splitpack2(p[4 * c + 0], p[4 * c + 1]);
      const uint2 s23 = splitpack2(p[4 * c + 2], p[4 * c + 3]);
      const int t = c >> 1, lh = c & 1;
      const int bi = (t * 64 + lh * 32 + l31) * 8 + lhi * 4;
      *(uint2*)&Pw[bi] = uint2{s01.x, s23.x};
      *(uint2*)&Pw[1024 + bi] = uint2{s01.y, s23.y};
    }

    // ---- O^T += V^T · P^T
#pragma unroll
    for (int t = 0; t < 2; ++t) {
      const bf16x8 ph = *(const bf16x8*)&Pw[(t * 64 + lane) * 8];
      const bf16x8 pl_ = *(const bf16x8*)&Pw[1024 + (t * 64 + lane) * 8];
      bf16x8 vh = *(const bf16x8*)&smem[VF0 +
          (((((hsel * 2 + 0) * 2 + wk) * 2 + 0) * 2 + t) * 64 + lane) * 8];
      bf16x8 vl = *(const bf16x8*)&smem[VF0 +
          (((((hsel * 2 + 1) * 2 + wk) * 2 + 0) * 2 + t) * 64 + lane) * 8];
      o0 = MFMA32(vh, ph, o0, 0, 0, 0);
      o0 = MFMA32(vh, pl_, o0, 0, 0, 0);
      o0 = MFMA32(vl, ph, o0, 0, 0, 0);
      vh = *(const bf16x8*)&smem[VF0 +
          (((((hsel * 2 + 0) * 2 + wk) * 2 + 1) * 2 + t) * 64 + lane) * 8];
      vl = *(const bf16x8*)&smem[VF0 +
          (((((hsel * 2 + 1) * 2 + wk) * 2 + 1) * 2 + t) * 64 + lane) * 8];
      o1 = MFMA32(vh, ph, o1, 0, 0, 0);
      o1 = MFMA32(vh, pl_, o1, 0, 0, 0);
      o1 = MFMA32(vl, ph, o1, 0, 0, 0);
    }
    __syncthreads();
  }

  // ---- merge wk=0/1 (same hsel,wq) through LDS (overlays Kf/Vf, dead now)
  float* mL = (float*)(smem + KF0);  // [2hsel*2wq*32] = 128
  float* lL = mL + 128;              // 128
  float* Om = lL + 128;              // [2][2][64][33]
  if (wk == 1) {
    if (lhi == 0) {
      mL[(hsel * 2 + wq) * 32 + l31] = m_run;
      lL[(hsel * 2 + wq) * 32 + l31] = l_run;
    }
#pragma unroll
    for (int mt = 0; mt < 2; ++mt)
#pragma unroll
      for (int r = 0; r < 16; ++r) {
        const int row = mt * 32 + (r & 3) + 8 * (r >> 2) + 4 * lhi;
        Om[((hsel * 2 + wq) * 64 + row) * 33 + l31] = (mt ? o1[r] : o0[r]);
      }
  }
  __syncthreads();
  if (wk == 0) {
    const float m1 = mL[(hsel * 2 + wq) * 32 + l31];
    const float l1v = lL[(hsel * 2 + wq) * 32 + l31];
    const float mst = fmaxf(m_run, m1);
    const float a0 = __expf(m_run - mst), a1 = __expf(m1 - mst);
    const float inv = 1.f / (a0 * l_run + a1 * l1v);
    const int tok = b * 2048 + qg;
#pragma unroll
    for (int mt = 0; mt < 2; ++mt)
#pragma unroll
      for (int r = 0; r < 16; ++r) {
        const int row = mt * 32 + (r & 3) + 8 * (r >> 2) + 4 * lhi;
        const float val = (a0 * (mt ? o1[r] : o0[r]) +
                           a1 * Om[((hsel * 2 + wq) * 64 + row) * 33 + l31]) *
                          inv;
        const int d = head * 64 + row;
        u16 hi, lo;
        split1(val, hi, lo);
        const size_t idx = ((size_t)(d >> 3) * 4096 + tok) * 8 + (d & 7);
        Othi[idx] = hi;
        Otlo[idx] = lo;
      }
  }
}

// ---------------------------------------------------------------------------
// GEMM2 (MFMA): out = o @ Wo^T + bo. A from Otc chunk planes (b128 staging),
// B = Wo fp32 converted inline. Tiles 64x64, BK=32, 4 waves (2x2), 1 tile ea.
// ---------------------------------------------------------------------------
__global__ __launch_bounds__(256, 2) void gemm2_mfma(
    const u16* __restrict__ Othi, const u16* __restrict__ Otlo,
    const float* __restrict__ Wo, const float* __restrict__ bo,
    float* __restrict__ out) {
  __shared__ __align__(16) u16 Af[2][2][2][64][8];  // 8 KB
  __shared__ __align__(16) u16 Bf[2][2][2][64][8];  // 8 KB
  const int tid = threadIdx.x;
  const int wave = tid >> 6, lane = tid & 63, l31 = lane & 31, lhi = lane >> 5;
  const int wm = wave >> 1, wn = wave & 1;
  const int m0 = blockIdx.y * 64, n0 = blockIdx.x * 64;

  f32x16 acc;
#pragma unroll
  for (int r = 0; r < 16; ++r) acc[r] = 0.f;

  for (int k0 = 0; k0 < 512; k0 += 32) {
#pragma unroll
    for (int i = 0; i < 2; ++i) {
      const int f = i * 256 + tid;
      const int p = f >> 8, rem = f & 255, c = rem >> 6, tok = rem & 63;
      const u16* src =
          (p ? Otlo : Othi) + ((size_t)(k0 / 8 + c) * 4096 + m0 + tok) * 8;
      *(uint4*)&Af[p][tok >> 5][c >> 1][(c & 1) * 32 + (tok & 31)][0] =
          *(const uint4*)src;
    }
    {
      const int n = tid >> 2, c = tid & 3;
      const float* src = Wo + (size_t)(n0 + n) * 512 + k0 + c * 8;
      const float4 v0 = *(const float4*)src;
      const float4 v1 = *(const float4*)(src + 4);
      const uint2 q0 = splitpack2(v0.x, v0.y), q1 = splitpack2(v0.z, v0.w);
      const uint2 q2 = splitpack2(v1.x, v1.y), q3 = splitpack2(v1.z, v1.w);
      *(uint4*)&Bf[0][n >> 5][c >> 1][(c & 1) * 32 + (n & 31)][0] =
          uint4{q0.x, q1.x, q2.x, q3.x};
      *(uint4*)&Bf[1][n >> 5][c >> 1][(c & 1) * 32 + (n & 31)][0] =
          uint4{q0.y, q1.y, q2.y, q3.y};
    }
    __syncthreads();
#pragma unroll
    for (int t = 0; t < 2; ++t) {
      const bf16x8 ah = *(const bf16x8*)&Af[0][wm][t][lane][0];
      const bf16x8 al = *(const bf16x8*)&Af[1][wm][t][lane][0];
      const bf16x8 bh = *(const bf16x8*)&Bf[0][wn][t][lane][0];
      const bf16x8 bl = *(const bf16x8*)&Bf[1][wn][t][lane][0];
      acc = MFMA32(ah, bh, acc, 0, 0, 0);
      acc = MFMA32(ah, bl, acc, 0, 0, 0);
      acc = MFMA32(al, bh, acc, 0, 0, 0);
    }
    __syncthreads();
  }

  const int n = n0 + wn * 32 + l31;
  const float bn = bo[n];
#pragma unroll
  for (int r = 0; r < 16; ++r) {
    const int m = m0 + wm * 32 + (r & 3) + 8 * (r >> 2) + 4 * lhi;
    out[(size_t)m * 512 + n] = acc[r] + bn;
  }
}

// ---------------------------------------------------------------------------
extern "C" void kernel_launch(void* const* d_in, const int* in_sizes, int n_in,
                              void* d_out, int out_size, void* d_ws,
                              size_t ws_size, hipStream_t stream) {
  const float* x = (const float*)d_in[0];
  const float* shift = (const float*)d_in[1];
  const float* mask = (const float*)d_in[2];
  const float* W = (const float*)d_in[3];
  const float* b = (const float*)d_in[4];
  const float* Wo = (const float*)d_in[5];
  const float* bo = (const float*)d_in[6];
  float* out = (float*)d_out;

  // ws (32 MiB): [0,6P) Q/K/V hi+lo planes, [6P,8P) Ot hi/lo chunk planes.
  const size_t P = (size_t)Hc * Bc * Sc * DHc;  // 2,097,152
  u16* ws0 = (u16*)d_ws;
  u16* Qhi = ws0;
  u16* Qlo = ws0 + P;
  u16* Khi = ws0 + 2 * P;
  u16* Klo = ws0 + 3 * P;
  u16* Vthi = ws0 + 4 * P;
  u16* Vtlo = ws0 + 5 * P;
  u16* Othi = ws0 + 6 * P;
  u16* Otlo = ws0 + 7 * P;

  // 1) QKV projection (MFMA, inline fp32->bf16 hi/lo split; Q pre-scaled)
  gemm1_mfma<<<dim3(NQKV / 64, (Bc * Sc) / 128), 256, 0, stream>>>(
      x, W, b, Qhi, Qlo, Khi, Klo, Vthi, Vtlo);

  // 2) MFMA flash attention (2 heads/block, coalesced staging) -> Ot planes
  attn_mfma<<<dim3(Sc / 64, Bc, Hc / 2), 512, 0, stream>>>(
      Qhi, Qlo, Khi, Klo, Vthi, Vtlo, shift, mask, Othi, Otlo);

  // 3) output projection (MFMA) -> out
  gemm2_mfma<<<dim3(Dc / 64, (Bc * Sc) / 64), 256, 0, stream>>>(Othi, Otlo, Wo,
                                                                bo, out);
}

// Round 10
// 286.129 us; speedup vs baseline: 1.4751x; 1.0440x over previous
//
#include <hip/hip_runtime.h>
#include <math.h>

// Problem constants (fixed by reference)
constexpr int Bc = 2, Sc = 2048, Dc = 512, Hc = 8, DHc = 64;
constexpr int NQKV = 3 * Dc;  // 1536

typedef unsigned short u16;
typedef unsigned int u32;
typedef __attribute__((ext_vector_type(8))) __bf16 bf16x8;
typedef __attribute__((ext_vector_type(16))) float f32x16;

#define MFMA32 __builtin_amdgcn_mfma_f32_32x32x16_bf16

// Truncation hi/lo split of two floats, packed: ret.x = (hi(b)<<16)|hi(a),
// ret.y = lo-pair. hi = truncate-to-bf16; lo = bf16(residual).
__device__ inline uint2 splitpack2(float a, float b) {
  u32 ua = __float_as_uint(a), ub = __float_as_uint(b);
  u32 hi = (ub & 0xFFFF0000u) | (ua >> 16);
  float ra = a - __uint_as_float(ua & 0xFFFF0000u);
  float rb = b - __uint_as_float(ub & 0xFFFF0000u);
  u32 lo = (__float_as_uint(rb) & 0xFFFF0000u) | (__float_as_uint(ra) >> 16);
  return uint2{hi, lo};
}
__device__ inline void split1(float v, u16& hi, u16& lo) {
  u32 u = __float_as_uint(v);
  hi = (u16)(u >> 16);
  float r = v - __uint_as_float(u & 0xFFFF0000u);
  lo = (u16)(__float_as_uint(r) >> 16);
}

// ---------------------------------------------------------------------------
// GEMM1 (MFMA): qkv = x @ W^T + b, fp32 inputs split to bf16 hi/lo inline.
// Tiles 128x64, BK=32, 4 waves (2x2), 2 m-tiles per wave.
// R10: epilogue stages the C tile (hi/lo u16) in LDS [token][dh] (pad 72,
// conflict-free) and stores fully coalesced: Q/K planes are contiguous 16 KB
// linear regions; V^T is 64 x 256B chunks. Replaces 64 scattered 2-B
// stores/thread (32 lines per wave-instr) that dominated gemm1's runtime.
// Q is pre-scaled by 0.125 (folds the 1/sqrt(DH) logit scale).
// ---------------------------------------------------------------------------
__global__ __launch_bounds__(256, 2) void gemm1_mfma(
    const float* __restrict__ x, const float* __restrict__ W,
    const float* __restrict__ bias, u16* __restrict__ Qhi,
    u16* __restrict__ Qlo, u16* __restrict__ Khi, u16* __restrict__ Klo,
    u16* __restrict__ Vthi, u16* __restrict__ Vtlo) {
  // pool: staging phase Af [0,8192) u16, Bf [8192,12288);
  // epilogue overlays Ep hi [0,9216), lo [9216,18432)  (pad-72 rows).
  __shared__ __align__(16) u16 pool[18432];  // 36 KB
  const int tid = threadIdx.x;
  const int wave = tid >> 6, lane = tid & 63, l31 = lane & 31, lhi = lane >> 5;
  const int wm = wave >> 1, wn = wave & 1;
  const int m0 = blockIdx.y * 128, n0 = blockIdx.x * 64;

  f32x16 acc[2];
#pragma unroll
  for (int r = 0; r < 16; ++r) {
    acc[0][r] = 0.f;
    acc[1][r] = 0.f;
  }

  for (int k0 = 0; k0 < 512; k0 += 32) {
    // stage A: 512 8-elem k-groups (128 m x 4), 2 per thread, split inline
#pragma unroll
    for (int i = 0; i < 2; ++i) {
      const int g = i * 256 + tid;
      const int m = g >> 2, kg = g & 3;
      const float* src = x + (size_t)(m0 + m) * 512 + k0 + kg * 8;
      const float4 v0 = *(const float4*)src;
      const float4 v1 = *(const float4*)(src + 4);
      const uint2 p0 = splitpack2(v0.x, v0.y), p1 = splitpack2(v0.z, v0.w);
      const uint2 p2 = splitpack2(v1.x, v1.y), p3 = splitpack2(v1.z, v1.w);
      const int row = (kg & 1) * 32 + (m & 31);
      *(uint4*)&pool[((((0 * 4 + (m >> 5)) * 2 + (kg >> 1)) * 64 + row)) * 8] =
          uint4{p0.x, p1.x, p2.x, p3.x};
      *(uint4*)&pool[((((1 * 4 + (m >> 5)) * 2 + (kg >> 1)) * 64 + row)) * 8] =
          uint4{p0.y, p1.y, p2.y, p3.y};
    }
    // stage B: 256 groups, 1 per thread
    {
      const int n = tid >> 2, kg = tid & 3;
      const float* src = W + (size_t)(n0 + n) * 512 + k0 + kg * 8;
      const float4 v0 = *(const float4*)src;
      const float4 v1 = *(const float4*)(src + 4);
      const uint2 p0 = splitpack2(v0.x, v0.y), p1 = splitpack2(v0.z, v0.w);
      const uint2 p2 = splitpack2(v1.x, v1.y), p3 = splitpack2(v1.z, v1.w);
      const int row = (kg & 1) * 32 + (n & 31);
      *(uint4*)&pool[8192 +
                     ((((0 * 2 + (n >> 5)) * 2 + (kg >> 1)) * 64 + row)) * 8] =
          uint4{p0.x, p1.x, p2.x, p3.x};
      *(uint4*)&pool[8192 +
                     ((((1 * 2 + (n >> 5)) * 2 + (kg >> 1)) * 64 + row)) * 8] =
          uint4{p0.y, p1.y, p2.y, p3.y};
    }
    __syncthreads();
#pragma unroll
    for (int t = 0; t < 2; ++t) {
      const bf16x8 bh =
          *(const bf16x8*)&pool[8192 + (((0 * 2 + wn) * 2 + t) * 64 + lane) * 8];
      const bf16x8 bl =
          *(const bf16x8*)&pool[8192 + (((1 * 2 + wn) * 2 + t) * 64 + lane) * 8];
#pragma unroll
      for (int ti = 0; ti < 2; ++ti) {
        const bf16x8 ah =
            *(const bf16x8*)&pool[(((0 * 4 + wm * 2 + ti) * 2 + t) * 64 + lane) * 8];
        const bf16x8 al =
            *(const bf16x8*)&pool[(((1 * 4 + wm * 2 + ti) * 2 + t) * 64 + lane) * 8];
        acc[ti] = MFMA32(ah, bh, acc[ti], 0, 0, 0);
        acc[ti] = MFMA32(ah, bl, acc[ti], 0, 0, 0);
        acc[ti] = MFMA32(al, bh, acc[ti], 0, 0, 0);
      }
    }
    __syncthreads();
  }

  // ---- epilogue: LDS-staged coalesced stores ----
  const int n = n0 + wn * 32 + l31;
  const float bn = bias[n];
  const int h = n0 / 192;          // uniform per block (192 = 3*64)
  const int t3 = (n0 % 192) / 64;  // uniform per block
  const int dh = wn * 32 + l31;
  const int batch = m0 >> 11;  // uniform (2048 % 128 == 0)
  const int s0 = m0 & 2047;
  const int hbq = h * 2 + batch;

#pragma unroll
  for (int ti = 0; ti < 2; ++ti)
#pragma unroll
    for (int r = 0; r < 16; ++r) {
      const int tl = wm * 64 + ti * 32 + (r & 3) + 8 * (r >> 2) + 4 * lhi;
      float val = acc[ti][r] + bn;
      if (t3 == 0) val *= 0.125f;  // fold logit scale into Q
      u16 hi, lo;
      split1(val, hi, lo);
      pool[tl * 72 + dh] = hi;
      pool[9216 + tl * 72 + dh] = lo;
    }
  __syncthreads();

  u16 *d0, *d1;
  if (t3 == 0) {
    d0 = Qhi;
    d1 = Qlo;
  } else if (t3 == 1) {
    d0 = Khi;
    d1 = Klo;
  } else {
    d0 = Vthi;
    d1 = Vtlo;
  }

  if (t3 != 2) {
    // Q/K plane: [hbq][s][dh] -> 128 tokens x 64 dh = 16 KB contiguous
    const size_t base = ((size_t)hbq * 2048 + s0) * 64;
#pragma unroll
    for (int p = 0; p < 2; ++p) {
      u16* dst = (p ? d1 : d0) + base;
#pragma unroll
      for (int j = 0; j < 4; ++j) {
        const int g = tid * 32 + j * 8;
        const int token = g >> 6, dh8 = g & 63;
        *(uint4*)(dst + g) = *(const uint4*)&pool[p * 9216 + token * 72 + dh8];
      }
    }
  } else {
    // V^T plane: [hbq][dh][s] -> 64 rows x 128 tokens (256 B chunks)
    const int d = tid >> 2, tp = (tid & 3) * 32;
#pragma unroll
    for (int p = 0; p < 2; ++p) {
      u16* dst = (p ? d1 : d0) + ((size_t)hbq * 64 + d) * 2048 + s0 + tp;
      u32 w[16];
#pragma unroll
      for (int j = 0; j < 16; ++j) {
        const u16 a = pool[p * 9216 + (tp + 2 * j) * 72 + d];
        const u16 b2 = pool[p * 9216 + (tp + 2 * j + 1) * 72 + d];
        w[j] = (u32)a | ((u32)b2 << 16);
      }
#pragma unroll
      for (int j = 0; j < 4; ++j)
        *(uint4*)(dst + j * 8) =
            uint4{w[4 * j], w[4 * j + 1], w[4 * j + 2], w[4 * j + 3]};
    }
  }
}

// ---------------------------------------------------------------------------
// MFMA flash attention (R9 winner, unchanged): 512-thread block = 8 waves =
// (hsel,wq,wk) handles TWO heads x 64 q. Coalesced staging; SM tile shared
// by both heads. LDS ~113 KB -> 1 block/CU. 2 barriers/iter.
// ---------------------------------------------------------------------------
constexpr int KF0 = 8320;   // u16 idx; Kf 16384 u16 (32 KB)
constexpr int VF0 = 24704;  // Vf 16384 u16 (32 KB)
constexpr int PF0 = 41088;  // Pf 16384 u16 (32 KB)

__global__ __launch_bounds__(512, 1) void attn_mfma(
    const u16* __restrict__ Qhi, const u16* __restrict__ Qlo,
    const u16* __restrict__ Khi, const u16* __restrict__ Klo,
    const u16* __restrict__ Vthi, const u16* __restrict__ Vtlo,
    const float* __restrict__ shift, const float* __restrict__ mask,
    u16* __restrict__ Othi, u16* __restrict__ Otlo) {
  const int hp = blockIdx.z, b = blockIdx.y, qb = blockIdx.x;
  const int tid = threadIdx.x;
  const int wave = tid >> 6;
  const int hsel = wave >> 2, wq = (wave >> 1) & 1, wk = wave & 1;
  const int lane = tid & 63;
  const int l31 = lane & 31, lhi = lane >> 5;

  __shared__ __align__(16) u16 smem[57472];  // 114944 B
  float* SMs = (float*)smem;                 // [64][65] transposed [k][q]
  u16* Pw = smem + PF0 + wave * 2048;        // wave P chunk: hi | lo+1024

  const int head = hp * 2 + hsel;
  const size_t hb = (size_t)head * Bc + b;
  const int ql = wq * 32 + l31;
  const int qg = qb * 64 + ql;

  // Q B-frags (pre-scaled): n=q, k = t*16 + lhi*8 + j
  bf16x8 qf[2][4];
  {
    const size_t qbase = (hb * Sc + qg) * DHc;
#pragma unroll
    for (int t = 0; t < 4; ++t) {
      qf[0][t] = *(const bf16x8*)(Qhi + qbase + t * 16 + lhi * 8);
      qf[1][t] = *(const bf16x8*)(Qlo + qbase + t * 16 + lhi * 8);
    }
  }
  const float hs = exp2f(-(float)head);

  // SM staging map: thread -> row q = tid>>3, cols (tid&7)*8 .. +7
  const int smq = tid >> 3, smk = (tid & 7) * 8;
  const float* shr = shift + ((size_t)b * Sc + qb * 64 + smq) * Sc + smk;
  const float* mkr = mask + ((size_t)b * Sc + qb * 64 + smq) * Sc + smk;

  // K staging (waves wq==0): 32 keys x 64 dh for head hsel, half wk
  const int kr = lane >> 1, kh2 = lane & 1;
  const size_t kfix = (hb * Sc + wk * 32 + kr) * 64 + kh2 * 32;
  // V staging (waves wq==1): lane = dh row
  const size_t vfix = (hb * 64 + lane) * 2048 + wk * 32;
  const int vmt = lane >> 5, vdl = lane & 31;

  float m_run = -INFINITY, l_run = 0.f;
  f32x16 o0, o1;
#pragma unroll
  for (int i = 0; i < 16; ++i) {
    o0[i] = 0.f;
    o1[i] = 0.f;
  }

  for (int it = 0; it < 32; ++it) {
    const int kt = it * 64;
    // ---- stage SM (all 512 threads): 2x(shift,mask) float4, fuse, store
    {
      const float4 s0 = *(const float4*)(shr + kt);
      const float4 s1 = *(const float4*)(shr + kt + 4);
      const float4 m0 = *(const float4*)(mkr + kt);
      const float4 m1 = *(const float4*)(mkr + kt + 4);
      float* dst = SMs + (size_t)smk * 65 + smq;
      dst[0 * 65] = (m0.x != 0.f) ? s0.x : 1e13f;
      dst[1 * 65] = (m0.y != 0.f) ? s0.y : 1e13f;
      dst[2 * 65] = (m0.z != 0.f) ? s0.z : 1e13f;
      dst[3 * 65] = (m0.w != 0.f) ? s0.w : 1e13f;
      dst[4 * 65] = (m1.x != 0.f) ? s1.x : 1e13f;
      dst[5 * 65] = (m1.y != 0.f) ? s1.y : 1e13f;
      dst[6 * 65] = (m1.z != 0.f) ? s1.z : 1e13f;
      dst[7 * 65] = (m1.w != 0.f) ? s1.w : 1e13f;
    }
    // ---- stage K (wq==0) / V^T (wq==1) for head hsel, half wk
    if (wq == 0) {
      const size_t gb = kfix + (size_t)kt * 64;
#pragma unroll
      for (int c = 0; c < 4; ++c) {
        const int dhc = kh2 * 32 + c * 8;
        const int t = dhc >> 4, lh = (dhc >> 3) & 1;
        *(uint4*)&smem[KF0 + ((((hsel * 2 + 0) * 2 + wk) * 4 + t) * 64 +
                              lh * 32 + kr) * 8] =
            *(const uint4*)(Khi + gb + c * 8);
        *(uint4*)&smem[KF0 + ((((hsel * 2 + 1) * 2 + wk) * 4 + t) * 64 +
                              lh * 32 + kr) * 8] =
            *(const uint4*)(Klo + gb + c * 8);
      }
    } else {
      const size_t gb = vfix + kt;
#pragma unroll
      for (int c = 0; c < 4; ++c) {
        const int t = c >> 1, lh = c & 1;
        *(uint4*)&smem[VF0 + (((((hsel * 2 + 0) * 2 + wk) * 2 + vmt) * 2 + t) *
                                  64 + lh * 32 + vdl) * 8] =
            *(const uint4*)(Vthi + gb + c * 8);
        *(uint4*)&smem[VF0 + (((((hsel * 2 + 1) * 2 + wk) * 2 + vmt) * 2 + t) *
                                  64 + lh * 32 + vdl) * 8] =
            *(const uint4*)(Vtlo + gb + c * 8);
      }
    }
    __syncthreads();

    // ---- S^T = K·Q^T (m=key32, n=q32): Khi*Qhi + Khi*Qlo + Klo*Qhi
    f32x16 s;
#pragma unroll
    for (int i = 0; i < 16; ++i) s[i] = 0.f;
#pragma unroll
    for (int t = 0; t < 4; ++t) {
      const bf16x8 kh = *(const bf16x8*)&smem[KF0 +
          ((((hsel * 2 + 0) * 2 + wk) * 4 + t) * 64 + lane) * 8];
      const bf16x8 kl = *(const bf16x8*)&smem[KF0 +
          ((((hsel * 2 + 1) * 2 + wk) * 4 + t) * 64 + lane) * 8];
      s = MFMA32(kh, qf[0][t], s, 0, 0, 0);
      s = MFMA32(kh, qf[1][t], s, 0, 0, 0);
      s = MFMA32(kl, qf[0][t], s, 0, 0, 0);
    }

    // ---- logits from SMs (conflict-free: lane l31 = q consecutive) + softmax
    float p[16];
    float kmax = -INFINITY;
#pragma unroll
    for (int c = 0; c < 4; ++c) {
#pragma unroll
      for (int e = 0; e < 4; ++e) {
        const int kl_ = wk * 32 + c * 8 + lhi * 4 + e;
        const float a = hs * SMs[(size_t)kl_ * 65 + ql];
        const float lg = s[4 * c + e] - a;
        p[4 * c + e] = lg;
        kmax = fmaxf(kmax, lg);
      }
    }
    kmax = fmaxf(kmax, __shfl_xor(kmax, 32, 64));
    const float mnew = fmaxf(m_run, kmax);
    const float alpha = __expf(m_run - mnew);
    float rsum = 0.f;
#pragma unroll
    for (int r = 0; r < 16; ++r) {
      p[r] = __expf(p[r] - mnew);
      rsum += p[r];
    }
    rsum += __shfl_xor(rsum, 32, 64);
    l_run = l_run * alpha + rsum;
    m_run = mnew;
#pragma unroll
    for (int i = 0; i < 16; ++i) {
      o0[i] *= alpha;
      o1[i] *= alpha;
    }

    // ---- P -> own LDS chunk (same-wave DS ordering; no barrier needed)
#pragma unroll
    for (int c = 0; c < 4; ++c) {
      const uint2 s01 = splitpack2(p[4 * c + 0], p[4 * c + 1]);
      const uint2 s23 = splitpack2(p[4 * c + 2], p[4 * c + 3]);
      const int t = c >> 1, lh = c & 1;
      const int bi = (t * 64 + lh * 32 + l31) * 8 + lhi * 4;
      *(uint2*)&Pw[bi] = uint2{s01.x, s23.x};
      *(uint2*)&Pw[1024 + bi] = uint2{s01.y, s23.y};
    }

    // ---- O^T += V^T · P^T
#pragma unroll
    for (int t = 0; t < 2; ++t) {
      const bf16x8 ph = *(const bf16x8*)&Pw[(t * 64 + lane) * 8];
      const bf16x8 pl_ = *(const bf16x8*)&Pw[1024 + (t * 64 + lane) * 8];
      bf16x8 vh = *(const bf16x8*)&smem[VF0 +
          (((((hsel * 2 + 0) * 2 + wk) * 2 + 0) * 2 + t) * 64 + lane) * 8];
      bf16x8 vl = *(const bf16x8*)&smem[VF0 +
          (((((hsel * 2 + 1) * 2 + wk) * 2 + 0) * 2 + t) * 64 + lane) * 8];
      o0 = MFMA32(vh, ph, o0, 0, 0, 0);
      o0 = MFMA32(vh, pl_, o0, 0, 0, 0);
      o0 = MFMA32(vl, ph, o0, 0, 0, 0);
      vh = *(const bf16x8*)&smem[VF0 +
          (((((hsel * 2 + 0) * 2 + wk) * 2 + 1) * 2 + t) * 64 + lane) * 8];
      vl = *(const bf16x8*)&smem[VF0 +
          (((((hsel * 2 + 1) * 2 + wk) * 2 + 1) * 2 + t) * 64 + lane) * 8];
      o1 = MFMA32(vh, ph, o1, 0, 0, 0);
      o1 = MFMA32(vh, pl_, o1, 0, 0, 0);
      o1 = MFMA32(vl, ph, o1, 0, 0, 0);
    }
    __syncthreads();
  }

  // ---- merge wk=0/1 (same hsel,wq) through LDS (overlays Kf/Vf, dead now)
  float* mL = (float*)(smem + KF0);  // 128
  float* lL = mL + 128;              // 128
  float* Om = lL + 128;              // [2][2][64][33]
  if (wk == 1) {
    if (lhi == 0) {
      mL[(hsel * 2 + wq) * 32 + l31] = m_run;
      lL[(hsel * 2 + wq) * 32 + l31] = l_run;
    }
#pragma unroll
    for (int mt = 0; mt < 2; ++mt)
#pragma unroll
      for (int r = 0; r < 16; ++r) {
        const int row = mt * 32 + (r & 3) + 8 * (r >> 2) + 4 * lhi;
        Om[((hsel * 2 + wq) * 64 + row) * 33 + l31] = (mt ? o1[r] : o0[r]);
      }
  }
  __syncthreads();
  if (wk == 0) {
    const float m1 = mL[(hsel * 2 + wq) * 32 + l31];
    const float l1v = lL[(hsel * 2 + wq) * 32 + l31];
    const float mst = fmaxf(m_run, m1);
    const float a0 = __expf(m_run - mst), a1 = __expf(m1 - mst);
    const float inv = 1.f / (a0 * l_run + a1 * l1v);
    const int tok = b * 2048 + qg;
#pragma unroll
    for (int mt = 0; mt < 2; ++mt)
#pragma unroll
      for (int r = 0; r < 16; ++r) {
        const int row = mt * 32 + (r & 3) + 8 * (r >> 2) + 4 * lhi;
        const float val = (a0 * (mt ? o1[r] : o0[r]) +
                           a1 * Om[((hsel * 2 + wq) * 64 + row) * 33 + l31]) *
                          inv;
        const int d = head * 64 + row;
        u16 hi, lo;
        split1(val, hi, lo);
        const size_t idx = ((size_t)(d >> 3) * 4096 + tok) * 8 + (d & 7);
        Othi[idx] = hi;
        Otlo[idx] = lo;
      }
  }
}

// ---------------------------------------------------------------------------
// GEMM2 (MFMA): out = o @ Wo^T + bo. A from Otc chunk planes (b128 staging),
// B = Wo fp32 converted inline. Tiles 64x64, BK=32, 4 waves (2x2), 1 tile ea.
// ---------------------------------------------------------------------------
__global__ __launch_bounds__(256, 2) void gemm2_mfma(
    const u16* __restrict__ Othi, const u16* __restrict__ Otlo,
    const float* __restrict__ Wo, const float* __restrict__ bo,
    float* __restrict__ out) {
  __shared__ __align__(16) u16 Af[2][2][2][64][8];  // 8 KB
  __shared__ __align__(16) u16 Bf[2][2][2][64][8];  // 8 KB
  const int tid = threadIdx.x;
  const int wave = tid >> 6, lane = tid & 63, l31 = lane & 31, lhi = lane >> 5;
  const int wm = wave >> 1, wn = wave & 1;
  const int m0 = blockIdx.y * 64, n0 = blockIdx.x * 64;

  f32x16 acc;
#pragma unroll
  for (int r = 0; r < 16; ++r) acc[r] = 0.f;

  for (int k0 = 0; k0 < 512; k0 += 32) {
#pragma unroll
    for (int i = 0; i < 2; ++i) {
      const int f = i * 256 + tid;
      const int p = f >> 8, rem = f & 255, c = rem >> 6, tok = rem & 63;
      const u16* src =
          (p ? Otlo : Othi) + ((size_t)(k0 / 8 + c) * 4096 + m0 + tok) * 8;
      *(uint4*)&Af[p][tok >> 5][c >> 1][(c & 1) * 32 + (tok & 31)][0] =
          *(const uint4*)src;
    }
    {
      const int n = tid >> 2, c = tid & 3;
      const float* src = Wo + (size_t)(n0 + n) * 512 + k0 + c * 8;
      const float4 v0 = *(const float4*)src;
      const float4 v1 = *(const float4*)(src + 4);
      const uint2 q0 = splitpack2(v0.x, v0.y), q1 = splitpack2(v0.z, v0.w);
      const uint2 q2 = splitpack2(v1.x, v1.y), q3 = splitpack2(v1.z, v1.w);
      *(uint4*)&Bf[0][n >> 5][c >> 1][(c & 1) * 32 + (n & 31)][0] =
          uint4{q0.x, q1.x, q2.x, q3.x};
      *(uint4*)&Bf[1][n >> 5][c >> 1][(c & 1) * 32 + (n & 31)][0] =
          uint4{q0.y, q1.y, q2.y, q3.y};
    }
    __syncthreads();
#pragma unroll
    for (int t = 0; t < 2; ++t) {
      const bf16x8 ah = *(const bf16x8*)&Af[0][wm][t][lane][0];
      const bf16x8 al = *(const bf16x8*)&Af[1][wm][t][lane][0];
      const bf16x8 bh = *(const bf16x8*)&Bf[0][wn][t][lane][0];
      const bf16x8 bl = *(const bf16x8*)&Bf[1][wn][t][lane][0];
      acc = MFMA32(ah, bh, acc, 0, 0, 0);
      acc = MFMA32(ah, bl, acc, 0, 0, 0);
      acc = MFMA32(al, bh, acc, 0, 0, 0);
    }
    __syncthreads();
  }

  const int n = n0 + wn * 32 + l31;
  const float bn = bo[n];
#pragma unroll
  for (int r = 0; r < 16; ++r) {
    const int m = m0 + wm * 32 + (r & 3) + 8 * (r >> 2) + 4 * lhi;
    out[(size_t)m * 512 + n] = acc[r] + bn;
  }
}

// ---------------------------------------------------------------------------
extern "C" void kernel_launch(void* const* d_in, const int* in_sizes, int n_in,
                              void* d_out, int out_size, void* d_ws,
                              size_t ws_size, hipStream_t stream) {
  const float* x = (const float*)d_in[0];
  const float* shift = (const float*)d_in[1];
  const float* mask = (const float*)d_in[2];
  const float* W = (const float*)d_in[3];
  const float* b = (const float*)d_in[4];
  const float* Wo = (const float*)d_in[5];
  const float* bo = (const float*)d_in[6];
  float* out = (float*)d_out;

  // ws (32 MiB): [0,6P) Q/K/V hi+lo planes, [6P,8P) Ot hi/lo chunk planes.
  const size_t P = (size_t)Hc * Bc * Sc * DHc;  // 2,097,152
  u16* ws0 = (u16*)d_ws;
  u16* Qhi = ws0;
  u16* Qlo = ws0 + P;
  u16* Khi = ws0 + 2 * P;
  u16* Klo = ws0 + 3 * P;
  u16* Vthi = ws0 + 4 * P;
  u16* Vtlo = ws0 + 5 * P;
  u16* Othi = ws0 + 6 * P;
  u16* Otlo = ws0 + 7 * P;

  // 1) QKV projection (MFMA, coalesced LDS-staged epilogue; Q pre-scaled)
  gemm1_mfma<<<dim3(NQKV / 64, (Bc * Sc) / 128), 256, 0, stream>>>(
      x, W, b, Qhi, Qlo, Khi, Klo, Vthi, Vtlo);

  // 2) MFMA flash attention (2 heads/block, coalesced staging) -> Ot planes
  attn_mfma<<<dim3(Sc / 64, Bc, Hc / 2), 512, 0, stream>>>(
      Qhi, Qlo, Khi, Klo, Vthi, Vtlo, shift, mask, Othi, Otlo);

  // 3) output projection (MFMA) -> out
  gemm2_mfma<<<dim3(Dc / 64, (Bc * Sc) / 64), 256, 0, stream>>>(Othi, Otlo, Wo,
                                                                bo, out);
}